// Round 1
// baseline (8555.091 us; speedup 1.0000x reference)
//
#include <hip/hip_runtime.h>
#include <hip/hip_bf16.h>

#define T_    256
#define B_    64
#define EMB_  300
#define HID_  256
#define G_    1024   // 4*HID
#define L_    20
#define M_    (T_*B_)  // 16384

// ---------------------------------------------------------------------------
// Kernel 1: xp[dir][t*B+b][g] = dot(emb[sent[t,b]], Wih_dir[g,:]) + b_dir[g]
// GEMM: M=16384 rows (gathered emb), N=2048 (fwd 1024 | bwd 1024), K=300.
// 64x64 tile, BK=16, 256 threads, 4x4 micro-tile per thread.
// ---------------------------------------------------------------------------
__global__ __launch_bounds__(256) void k_xproj(
    const float* __restrict__ emb,
    const float* __restrict__ Wih_f, const float* __restrict__ b_f,
    const float* __restrict__ Wih_b, const float* __restrict__ b_b,
    const int*   __restrict__ sent,
    float* __restrict__ xp)
{
    __shared__ float As[16][68];   // [k][m], pad 68 keeps float4 align + low conflicts
    __shared__ float Bs[16][68];   // [k][n]
    __shared__ int   words[64];

    const int tid = threadIdx.x;
    const int n0  = blockIdx.x * 64;   // 0..2047
    const int m0  = blockIdx.y * 64;
    const int dir = n0 >> 10;          // 64 | 1024 -> tile never crosses boundary
    const int g0  = n0 & 1023;
    const float* __restrict__ Wih  = dir ? Wih_b : Wih_f;
    const float* __restrict__ bias = dir ? b_b   : b_f;

    if (tid < 64) words[tid] = sent[m0 + tid];
    __syncthreads();

    const int r = tid >> 2;          // 0..63 (row within tile)
    const int q = tid & 3;           // 0..3  (quad of 4 floats in k)
    const float* aptr = emb + (size_t)words[r] * EMB_ + q * 4;
    const float* bptr = Wih + (size_t)(g0 + r) * EMB_ + q * 4;

    const int tx = tid & 15;         // n micro
    const int ty = tid >> 4;         // m micro
    float acc[4][4] = {};

    for (int k0 = 0; k0 < 304; k0 += 16) {
        const int k = k0 + q * 4;
        float4 av = make_float4(0.f, 0.f, 0.f, 0.f);
        float4 bv = make_float4(0.f, 0.f, 0.f, 0.f);
        if (k < 300) {               // k%4==0 and 300%4==0 -> full float4 safe
            av = *(const float4*)(aptr + k0);
            bv = *(const float4*)(bptr + k0);
        }
        As[q*4+0][r] = av.x; As[q*4+1][r] = av.y; As[q*4+2][r] = av.z; As[q*4+3][r] = av.w;
        Bs[q*4+0][r] = bv.x; Bs[q*4+1][r] = bv.y; Bs[q*4+2][r] = bv.z; Bs[q*4+3][r] = bv.w;
        __syncthreads();
        #pragma unroll
        for (int kk = 0; kk < 16; ++kk) {
            const float4 a = *(const float4*)&As[kk][ty * 4];
            const float4 b = *(const float4*)&Bs[kk][tx * 4];
            acc[0][0] += a.x*b.x; acc[0][1] += a.x*b.y; acc[0][2] += a.x*b.z; acc[0][3] += a.x*b.w;
            acc[1][0] += a.y*b.x; acc[1][1] += a.y*b.y; acc[1][2] += a.y*b.z; acc[1][3] += a.y*b.w;
            acc[2][0] += a.z*b.x; acc[2][1] += a.z*b.y; acc[2][2] += a.z*b.z; acc[2][3] += a.z*b.w;
            acc[3][0] += a.w*b.x; acc[3][1] += a.w*b.y; acc[3][2] += a.w*b.z; acc[3][3] += a.w*b.w;
        }
        __syncthreads();
    }

    float* out = xp + (size_t)dir * M_ * G_;
    const int g = g0 + tx * 4;
    const float4 bs4 = *(const float4*)(bias + g);
    #pragma unroll
    for (int im = 0; im < 4; ++im) {
        const int m = m0 + ty * 4 + im;
        float4 rv;
        rv.x = acc[im][0] + bs4.x;
        rv.y = acc[im][1] + bs4.y;
        rv.z = acc[im][2] + bs4.z;
        rv.w = acc[im][3] + bs4.w;
        *(float4*)(out + (size_t)m * G_ + g) = rv;
    }
}

// ---------------------------------------------------------------------------
// Kernel 2: one LSTM time step, both directions (fwd at t=step, bwd at T-1-step).
// Block owns 16 hidden units x 16 batches, all 4 gates (no cross-block deps).
// grid = (16 j-tiles, 4 b-tiles, 2 dirs), 256 threads.
// ---------------------------------------------------------------------------
__device__ __forceinline__ float sigmoidf_(float x) { return 1.f / (1.f + __expf(-x)); }

__global__ __launch_bounds__(256) void k_lstm_step(
    const float* __restrict__ Whh_f, const float* __restrict__ Whh_b,
    const float* __restrict__ xp,    // [2][T*B][G]
    float* __restrict__ hbuf,        // [2][T*B][H]
    float* __restrict__ cbuf,        // [2][B][H]
    int step)
{
    const int dir   = blockIdx.z;
    const int t_eff = (dir == 0) ? step : (T_ - 1 - step);
    const float* __restrict__ Whh = dir ? Whh_b : Whh_f;
    float* __restrict__ hdir = hbuf + (size_t)dir * M_ * HID_;
    float* __restrict__ cdir = cbuf + (size_t)dir * B_ * HID_;
    const float* __restrict__ xpt = xp + (size_t)dir * M_ * G_ + (size_t)t_eff * B_ * G_;

    const int j0 = blockIdx.x * 16;
    const int b0 = blockIdx.y * 16;
    const int tid = threadIdx.x;

    __shared__ float hs[16][260];   // h(t-1) tile, stride 260: conflict-free + 16B aligned

    if (step > 0) {
        const int tprev = (dir == 0) ? (t_eff - 1) : (t_eff + 1);
        const float* hp = hdir + (size_t)tprev * B_ * HID_;
        const int rr = tid >> 4;           // 0..15 row
        const int cc = (tid & 15) * 16;    // 16 floats per thread
        const float4* src = (const float4*)(hp + (size_t)(b0 + rr) * HID_ + cc);
        float4* dst = (float4*)&hs[rr][cc];
        dst[0] = src[0]; dst[1] = src[1]; dst[2] = src[2]; dst[3] = src[3];
    }
    __syncthreads();

    const int j_l = tid & 15, b_l = tid >> 4;
    const int j = j0 + j_l, b = b0 + b_l;

    float a0 = xpt[b * G_ + 0*HID_ + j];
    float a1 = xpt[b * G_ + 1*HID_ + j];
    float a2 = xpt[b * G_ + 2*HID_ + j];
    float a3 = xpt[b * G_ + 3*HID_ + j];

    float cprev = 0.f;
    if (step > 0) {
        cprev = cdir[b * HID_ + j];
        const float4* w0 = (const float4*)(Whh + (size_t)(0*HID_ + j) * HID_);
        const float4* w1 = (const float4*)(Whh + (size_t)(1*HID_ + j) * HID_);
        const float4* w2 = (const float4*)(Whh + (size_t)(2*HID_ + j) * HID_);
        const float4* w3 = (const float4*)(Whh + (size_t)(3*HID_ + j) * HID_);
        const float4* hv = (const float4*)&hs[b_l][0];
        #pragma unroll 8
        for (int k4 = 0; k4 < 64; ++k4) {
            const float4 h4 = hv[k4];
            float4 w;
            w = w0[k4]; a0 += h4.x*w.x + h4.y*w.y + h4.z*w.z + h4.w*w.w;
            w = w1[k4]; a1 += h4.x*w.x + h4.y*w.y + h4.z*w.z + h4.w*w.w;
            w = w2[k4]; a2 += h4.x*w.x + h4.y*w.y + h4.z*w.z + h4.w*w.w;
            w = w3[k4]; a3 += h4.x*w.x + h4.y*w.y + h4.z*w.z + h4.w*w.w;
        }
    }

    const float ig = sigmoidf_(a0);
    const float fg = sigmoidf_(a1);
    const float gg = tanhf(a2);
    const float og = sigmoidf_(a3);
    const float cn = fg * cprev + ig * gg;
    const float hn = og * tanhf(cn);

    cdir[b * HID_ + j] = cn;
    hdir[(size_t)t_eff * B_ * HID_ + b * HID_ + j] = hn;
}

// ---------------------------------------------------------------------------
// Kernel 3: emissions[t,b,l] = b_top[l] + h_f . W_top[l,0:256] + h_b . W_top[l,256:512]
// ---------------------------------------------------------------------------
__global__ __launch_bounds__(256) void k_emis(
    const float* __restrict__ Wt, const float* __restrict__ bt,
    const float* __restrict__ hbuf, float* __restrict__ em)
{
    const int gid = blockIdx.x * 256 + threadIdx.x;
    if (gid >= M_ * L_) return;
    const int m = gid / L_;
    const int l = gid - m * L_;
    const float4* hf  = (const float4*)(hbuf + (size_t)m * HID_);
    const float4* hbk = (const float4*)(hbuf + (size_t)M_ * HID_ + (size_t)m * HID_);
    const float4* w0  = (const float4*)(Wt + (size_t)l * 2 * HID_);
    const float4* w1  = w0 + HID_ / 4;
    float acc = bt[l];
    #pragma unroll 4
    for (int k = 0; k < HID_ / 4; ++k) {
        float4 h = hf[k],  w = w0[k];
        acc += h.x*w.x + h.y*w.y + h.z*w.z + h.w*w.w;
        h = hbk[k]; w = w1[k];
        acc += h.x*w.x + h.y*w.y + h.z*w.z + h.w*w.w;
    }
    em[gid] = acc;
}

// ---------------------------------------------------------------------------
// Kernel 4: CRF per-sequence forward algorithm + gold score. One block per b.
// ---------------------------------------------------------------------------
__global__ __launch_bounds__(64) void k_crf(
    const float* __restrict__ start_t, const float* __restrict__ end_t,
    const float* __restrict__ trans,
    const int* __restrict__ sent, const int* __restrict__ labels,
    const float* __restrict__ em, float* __restrict__ res)
{
    const int b = blockIdx.x;
    const int tid = threadIdx.x;
    __shared__ float tr[L_ * L_];
    __shared__ float alpha[2][L_];
    __shared__ float red[64];
    __shared__ int   redi[64];
    __shared__ float sdenom;

    for (int i = tid; i < L_ * L_; i += 64) tr[i] = trans[i];
    if (tid < L_) alpha[0][tid] = start_t[tid] + em[b * L_ + tid];
    __syncthreads();

    int p = 0;
    for (int t = 1; t < T_; ++t) {
        float val = 0.f;
        if (tid < L_) {
            if (sent[t * B_ + b] != 0) {
                float mx = -1e30f;
                #pragma unroll
                for (int i = 0; i < L_; ++i) mx = fmaxf(mx, alpha[p][i] + tr[i * L_ + tid]);
                float s = 0.f;
                #pragma unroll
                for (int i = 0; i < L_; ++i) s += __expf(alpha[p][i] + tr[i * L_ + tid] - mx);
                val = mx + __logf(s) + em[(t * B_ + b) * L_ + tid];
            } else {
                val = alpha[p][tid];
            }
        }
        if (tid < L_) alpha[1 - p][tid] = val;
        __syncthreads();
        p ^= 1;
    }

    if (tid == 0) {
        float mx = -1e30f;
        for (int j = 0; j < L_; ++j) mx = fmaxf(mx, alpha[p][j] + end_t[j]);
        float s = 0.f;
        for (int j = 0; j < L_; ++j) s += __expf(alpha[p][j] + end_t[j] - mx);
        sdenom = mx + __logf(s);
    }

    // gold-path score partials over t
    float loc = 0.f;
    int   cnt = 0;
    for (int t = tid; t < T_; t += 64) {
        const int masked = (sent[t * B_ + b] != 0);
        cnt += masked;
        if (t >= 1 && masked) {
            const int tp = labels[(t - 1) * B_ + b];
            const int tc = labels[t * B_ + b];
            loc += tr[tp * L_ + tc] + em[(t * B_ + b) * L_ + tc];
        }
    }
    red[tid] = loc; redi[tid] = cnt;
    __syncthreads();
    if (tid == 0) {
        float s = 0.f; int c = 0;
        for (int i = 0; i < 64; ++i) { s += red[i]; c += redi[i]; }
        const int tag0 = labels[b];
        const int seq_end = c - 1;                  // reference: mask.sum(0)-1
        const int last = labels[seq_end * B_ + b];
        const float score = start_t[tag0] + em[b * L_ + tag0] + s + end_t[last];
        res[b] = score - sdenom;
    }
}

// ---------------------------------------------------------------------------
// Kernel 5: final reduction over batch -> out[0] = -sum(score - denom)
// ---------------------------------------------------------------------------
__global__ __launch_bounds__(64) void k_final(const float* __restrict__ res,
                                              float* __restrict__ out)
{
    __shared__ float red[64];
    red[threadIdx.x] = res[threadIdx.x];
    __syncthreads();
    if (threadIdx.x == 0) {
        float s = 0.f;
        for (int i = 0; i < 64; ++i) s += red[i];
        out[0] = -s;
    }
}

// ---------------------------------------------------------------------------
extern "C" void kernel_launch(void* const* d_in, const int* in_sizes, int n_in,
                              void* d_out, int out_size, void* d_ws, size_t ws_size,
                              hipStream_t stream)
{
    const float* emb     = (const float*)d_in[0];
    const float* Wih_f   = (const float*)d_in[1];
    const float* Whh_f   = (const float*)d_in[2];
    const float* b_f     = (const float*)d_in[3];
    const float* Wih_b   = (const float*)d_in[4];
    const float* Whh_b   = (const float*)d_in[5];
    const float* b_b     = (const float*)d_in[6];
    const float* W_top   = (const float*)d_in[7];
    const float* b_top   = (const float*)d_in[8];
    const float* start_t = (const float*)d_in[9];
    const float* end_t   = (const float*)d_in[10];
    const float* trans   = (const float*)d_in[11];
    const int*   sent    = (const int*)d_in[12];
    const int*   labels  = (const int*)d_in[13];
    float* out = (float*)d_out;

    // workspace layout (floats): total ~169 MB
    float* wsf  = (float*)d_ws;
    float* xp   = wsf;                                   // 2*M*G  = 33,554,432
    float* hbuf = xp   + (size_t)2 * M_ * G_;            // 2*M*H  =  8,388,608
    float* cbuf = hbuf + (size_t)2 * M_ * HID_;          // 2*B*H  =     32,768
    float* em   = cbuf + (size_t)2 * B_ * HID_;          // M*L    =    327,680
    float* res  = em   + (size_t)M_ * L_;                // B      =         64

    // 1) input projection GEMM (both dirs)
    k_xproj<<<dim3(2048 / 64, M_ / 64), 256, 0, stream>>>(
        emb, Wih_f, b_f, Wih_b, b_b, sent, xp);

    // 2) sequential LSTM scans, fwd + bwd in the same launch
    for (int step = 0; step < T_; ++step) {
        k_lstm_step<<<dim3(HID_ / 16, B_ / 16, 2), 256, 0, stream>>>(
            Whh_f, Whh_b, xp, hbuf, cbuf, step);
    }

    // 3) emissions
    k_emis<<<(M_ * L_ + 255) / 256, 256, 0, stream>>>(W_top, b_top, hbuf, em);

    // 4) CRF per-sequence
    k_crf<<<B_, 64, 0, stream>>>(start_t, end_t, trans, sent, labels, em, res);

    // 5) final sum
    k_final<<<1, 64, 0, stream>>>(res, out);
}

// Round 2
// 5562.005 us; speedup vs baseline: 1.5381x; 1.5381x over previous
//
#include <hip/hip_runtime.h>
#include <hip/hip_bf16.h>

#define T_    256
#define B_    64
#define EMB_  300
#define HID_  256
#define G_    1024   // 4*HID
#define L_    20
#define M_    (T_*B_)  // 16384

// scan decomposition
#define NCL   16      // clusters = 2 dirs x 8 batch-groups
#define CLB   16      // blocks per cluster (16 units each)
#define BPC   8       // batches per cluster
#define UPB   16      // hidden units per block

// ---------------------------------------------------------------------------
// Kernel 1: xp[dir][t*B+b][g] = dot(emb[sent[t,b]], Wih_dir[g,:]) + b_dir[g]
// ---------------------------------------------------------------------------
__global__ __launch_bounds__(256) void k_xproj(
    const float* __restrict__ emb,
    const float* __restrict__ Wih_f, const float* __restrict__ b_f,
    const float* __restrict__ Wih_b, const float* __restrict__ b_b,
    const int*   __restrict__ sent,
    float* __restrict__ xp)
{
    __shared__ float As[16][68];
    __shared__ float Bs[16][68];
    __shared__ int   words[64];

    const int tid = threadIdx.x;
    const int n0  = blockIdx.x * 64;
    const int m0  = blockIdx.y * 64;
    const int dir = n0 >> 10;
    const int g0  = n0 & 1023;
    const float* __restrict__ Wih  = dir ? Wih_b : Wih_f;
    const float* __restrict__ bias = dir ? b_b   : b_f;

    if (tid < 64) words[tid] = sent[m0 + tid];
    __syncthreads();

    const int r = tid >> 2;
    const int q = tid & 3;
    const float* aptr = emb + (size_t)words[r] * EMB_ + q * 4;
    const float* bptr = Wih + (size_t)(g0 + r) * EMB_ + q * 4;

    const int tx = tid & 15;
    const int ty = tid >> 4;
    float acc[4][4] = {};

    for (int k0 = 0; k0 < 304; k0 += 16) {
        const int k = k0 + q * 4;
        float4 av = make_float4(0.f, 0.f, 0.f, 0.f);
        float4 bv = make_float4(0.f, 0.f, 0.f, 0.f);
        if (k < 300) {
            av = *(const float4*)(aptr + k0);
            bv = *(const float4*)(bptr + k0);
        }
        As[q*4+0][r] = av.x; As[q*4+1][r] = av.y; As[q*4+2][r] = av.z; As[q*4+3][r] = av.w;
        Bs[q*4+0][r] = bv.x; Bs[q*4+1][r] = bv.y; Bs[q*4+2][r] = bv.z; Bs[q*4+3][r] = bv.w;
        __syncthreads();
        #pragma unroll
        for (int kk = 0; kk < 16; ++kk) {
            const float4 a = *(const float4*)&As[kk][ty * 4];
            const float4 b = *(const float4*)&Bs[kk][tx * 4];
            acc[0][0] += a.x*b.x; acc[0][1] += a.x*b.y; acc[0][2] += a.x*b.z; acc[0][3] += a.x*b.w;
            acc[1][0] += a.y*b.x; acc[1][1] += a.y*b.y; acc[1][2] += a.y*b.z; acc[1][3] += a.y*b.w;
            acc[2][0] += a.z*b.x; acc[2][1] += a.z*b.y; acc[2][2] += a.z*b.z; acc[2][3] += a.z*b.w;
            acc[3][0] += a.w*b.x; acc[3][1] += a.w*b.y; acc[3][2] += a.w*b.z; acc[3][3] += a.w*b.w;
        }
        __syncthreads();
    }

    float* out = xp + (size_t)dir * M_ * G_;
    const int g = g0 + tx * 4;
    const float4 bs4 = *(const float4*)(bias + g);
    #pragma unroll
    for (int im = 0; im < 4; ++im) {
        const int m = m0 + ty * 4 + im;
        float4 rv;
        rv.x = acc[im][0] + bs4.x;
        rv.y = acc[im][1] + bs4.y;
        rv.z = acc[im][2] + bs4.z;
        rv.w = acc[im][3] + bs4.w;
        *(float4*)(out + (size_t)m * G_ + g) = rv;
    }
}

// ---------------------------------------------------------------------------
// Kernel 2: full bidirectional LSTM scan in ONE cooperative launch.
// 256 blocks = 16 clusters (dir x 8-batch group) x 16 blocks (16 units each).
// Whh lives entirely in registers (2 MB across 65536 threads x 16 float4).
// Per step: reg-MAC vs LDS h-tile -> shfl k-reduce -> gates -> h store ->
// cluster barrier (monotonic device-scope counter) -> reload h-tile.
// ---------------------------------------------------------------------------
__global__ __launch_bounds__(256) void k_lstm_scan(
    const float* __restrict__ Whh_f, const float* __restrict__ Whh_b,
    const float* __restrict__ xp, float* __restrict__ hbuf,
    unsigned int* __restrict__ cnt)
{
    const int cl   = blockIdx.x >> 4;       // 0..15
    const int rank = blockIdx.x & 15;       // unit-group within cluster
    const int dir  = cl >> 3;
    const int bg   = cl & 7;
    const int b0   = bg * BPC;
    const int u0   = rank * UPB;
    const int tid  = threadIdx.x;
    const int lane = tid & 63;
    const int wave = tid >> 6;      // == gate index g (i,f,g,o)
    const int r16  = lane & 15;     // unit within block
    const int kq   = lane >> 4;     // k-quarter (64 k each)

    const float* __restrict__ Whh = dir ? Whh_b : Whh_f;
    const float* __restrict__ xpd = xp + (size_t)dir * M_ * G_;
    float* __restrict__ hdir = hbuf + (size_t)dir * M_ * HID_;

    __shared__ float hs[BPC][272];     // h-tile, kq-slices at stride 68 (bank-spread, 16B aligned)
    __shared__ float Cg[64][9];        // gate pre-activations [g*16+u][b]
    __shared__ float cs[BPC][UPB + 1]; // cell state

    for (int i = tid; i < BPC * 272; i += 256) ((float*)hs)[i] = 0.f;
    if (tid < BPC * (UPB + 1)) ((float*)cs)[tid] = 0.f;

    // permanent register-resident Whh slice: row (g*256 + u0 + r16), k in [64*kq, 64*kq+64)
    float4 wv[16];
    {
        const float* wrow = Whh + (size_t)(wave * HID_ + u0 + r16) * HID_ + kq * 64;
        #pragma unroll
        for (int i = 0; i < 16; ++i) wv[i] = ((const float4*)wrow)[i];
    }
    __syncthreads();

    const int eu = tid & 15;           // epilogue unit (contiguous lanes -> coalesced)
    const int eb = (tid >> 4) & 7;     // epilogue batch

    unsigned int target = 0;
    for (int t = 0; t < T_; ++t) {
        const int t_eff = dir ? (T_ - 1 - t) : t;

        // prefetch this step's xp gates (latency hides under the MAC loop)
        float x0 = 0.f, x1 = 0.f, x2 = 0.f, x3 = 0.f;
        if (tid < 128) {
            const float* xrow = xpd + ((size_t)t_eff * B_ + (b0 + eb)) * G_ + (u0 + eu);
            x0 = xrow[0]; x1 = xrow[HID_]; x2 = xrow[2 * HID_]; x3 = xrow[3 * HID_];
        }

        // gate GEMM: acc[b][row] = sum_k Whh[row][k] * h_prev[b][k]
        #pragma unroll 2
        for (int b = 0; b < BPC; ++b) {
            const float4* hv = (const float4*)&hs[b][kq * 68];
            float acc = 0.f;
            #pragma unroll
            for (int i = 0; i < 16; ++i) {
                const float4 h4 = hv[i];
                const float4 w4 = wv[i];
                acc += w4.x * h4.x + w4.y * h4.y + w4.z * h4.z + w4.w * h4.w;
            }
            acc += __shfl_xor(acc, 16);
            acc += __shfl_xor(acc, 32);
            if (kq == 0) Cg[wave * 16 + r16][b] = acc;
        }
        __syncthreads();

        if (tid < 128) {
            const float gi = Cg[0 * 16 + eu][eb] + x0;
            const float gf = Cg[1 * 16 + eu][eb] + x1;
            const float gg = Cg[2 * 16 + eu][eb] + x2;
            const float go = Cg[3 * 16 + eu][eb] + x3;
            const float i_ = 1.f / (1.f + __expf(-gi));
            const float f_ = 1.f / (1.f + __expf(-gf));
            const float g_ = tanhf(gg);
            const float o_ = 1.f / (1.f + __expf(-go));
            const float cn = f_ * cs[eb][eu] + i_ * g_;
            const float hn = o_ * tanhf(cn);
            cs[eb][eu] = cn;
            hdir[((size_t)t_eff * B_ + (b0 + eb)) * HID_ + (u0 + eu)] = hn;
        }
        __syncthreads();   // s_barrier drains vmcnt: all h stores complete in L2

        if (t == T_ - 1) break;

        // cluster barrier: release(h stores) -> arrive -> spin -> acquire
        target += CLB;
        if (tid == 0) {
            __threadfence();   // agent release: L2 writeback -> h visible at L3
            __hip_atomic_fetch_add(&cnt[cl], 1u, __ATOMIC_RELAXED, __HIP_MEMORY_SCOPE_AGENT);
            while (__hip_atomic_load(&cnt[cl], __ATOMIC_RELAXED, __HIP_MEMORY_SCOPE_AGENT) < target)
                __builtin_amdgcn_s_sleep(2);
            __threadfence();   // agent acquire: invalidate stale L1/L2 lines
        }
        __syncthreads();

        // reload full h-tile for this cluster's 8 batches (written by all 16 peer blocks)
        {
            const float* hsrc = hdir + (size_t)t_eff * B_ * HID_ + (size_t)b0 * HID_;
            #pragma unroll
            for (int i = 0; i < 2; ++i) {
                const int idx = i * 256 + tid;     // 0..511 float4s
                const int b = idx >> 6, k4 = idx & 63;
                const float4 v = ((const float4*)(hsrc + b * HID_))[k4];
                const int kqq = k4 >> 4, off = (k4 & 15) * 4;
                *(float4*)&hs[b][kqq * 68 + off] = v;
            }
        }
        __syncthreads();
    }
}

// ---------------------------------------------------------------------------
// Kernel 3: emissions[t,b,l] = b_top[l] + h_f . W_top[l,:256] + h_b . W_top[l,256:]
// ---------------------------------------------------------------------------
__global__ __launch_bounds__(256) void k_emis(
    const float* __restrict__ Wt, const float* __restrict__ bt,
    const float* __restrict__ hbuf, float* __restrict__ em)
{
    const int gid = blockIdx.x * 256 + threadIdx.x;
    if (gid >= M_ * L_) return;
    const int m = gid / L_;
    const int l = gid - m * L_;
    const float4* hf  = (const float4*)(hbuf + (size_t)m * HID_);
    const float4* hbk = (const float4*)(hbuf + (size_t)M_ * HID_ + (size_t)m * HID_);
    const float4* w0  = (const float4*)(Wt + (size_t)l * 2 * HID_);
    const float4* w1  = w0 + HID_ / 4;
    float acc = bt[l];
    #pragma unroll 4
    for (int k = 0; k < HID_ / 4; ++k) {
        float4 h = hf[k],  w = w0[k];
        acc += h.x*w.x + h.y*w.y + h.z*w.z + h.w*w.w;
        h = hbk[k]; w = w1[k];
        acc += h.x*w.x + h.y*w.y + h.z*w.z + h.w*w.w;
    }
    em[gid] = acc;
}

// ---------------------------------------------------------------------------
// Kernel 4: CRF per-sequence forward + gold score. One block per b.
// ---------------------------------------------------------------------------
__global__ __launch_bounds__(64) void k_crf(
    const float* __restrict__ start_t, const float* __restrict__ end_t,
    const float* __restrict__ trans,
    const int* __restrict__ sent, const int* __restrict__ labels,
    const float* __restrict__ em, float* __restrict__ res)
{
    const int b = blockIdx.x;
    const int tid = threadIdx.x;
    __shared__ float tr[L_ * L_];
    __shared__ float alpha[2][L_];
    __shared__ float red[64];
    __shared__ int   redi[64];
    __shared__ float sdenom;

    for (int i = tid; i < L_ * L_; i += 64) tr[i] = trans[i];
    if (tid < L_) alpha[0][tid] = start_t[tid] + em[b * L_ + tid];
    __syncthreads();

    int p = 0;
    for (int t = 1; t < T_; ++t) {
        float val = 0.f;
        if (tid < L_) {
            if (sent[t * B_ + b] != 0) {
                float mx = -1e30f;
                #pragma unroll
                for (int i = 0; i < L_; ++i) mx = fmaxf(mx, alpha[p][i] + tr[i * L_ + tid]);
                float s = 0.f;
                #pragma unroll
                for (int i = 0; i < L_; ++i) s += __expf(alpha[p][i] + tr[i * L_ + tid] - mx);
                val = mx + __logf(s) + em[(t * B_ + b) * L_ + tid];
            } else {
                val = alpha[p][tid];
            }
        }
        if (tid < L_) alpha[1 - p][tid] = val;
        __syncthreads();
        p ^= 1;
    }

    if (tid == 0) {
        float mx = -1e30f;
        for (int j = 0; j < L_; ++j) mx = fmaxf(mx, alpha[p][j] + end_t[j]);
        float s = 0.f;
        for (int j = 0; j < L_; ++j) s += __expf(alpha[p][j] + end_t[j] - mx);
        sdenom = mx + __logf(s);
    }

    float loc = 0.f;
    int   cnt = 0;
    for (int t = tid; t < T_; t += 64) {
        const int masked = (sent[t * B_ + b] != 0);
        cnt += masked;
        if (t >= 1 && masked) {
            const int tp = labels[(t - 1) * B_ + b];
            const int tc = labels[t * B_ + b];
            loc += tr[tp * L_ + tc] + em[(t * B_ + b) * L_ + tc];
        }
    }
    red[tid] = loc; redi[tid] = cnt;
    __syncthreads();
    if (tid == 0) {
        float s = 0.f; int c = 0;
        for (int i = 0; i < 64; ++i) { s += red[i]; c += redi[i]; }
        const int tag0 = labels[b];
        const int seq_end = c - 1;
        const int last = labels[seq_end * B_ + b];
        const float score = start_t[tag0] + em[b * L_ + tag0] + s + end_t[last];
        res[b] = score - sdenom;
    }
}

// ---------------------------------------------------------------------------
// Kernel 5: out[0] = -sum_b res[b]
// ---------------------------------------------------------------------------
__global__ __launch_bounds__(64) void k_final(const float* __restrict__ res,
                                              float* __restrict__ out)
{
    __shared__ float red[64];
    red[threadIdx.x] = res[threadIdx.x];
    __syncthreads();
    if (threadIdx.x == 0) {
        float s = 0.f;
        for (int i = 0; i < 64; ++i) s += red[i];
        out[0] = -s;
    }
}

// ---------------------------------------------------------------------------
extern "C" void kernel_launch(void* const* d_in, const int* in_sizes, int n_in,
                              void* d_out, int out_size, void* d_ws, size_t ws_size,
                              hipStream_t stream)
{
    const float* emb     = (const float*)d_in[0];
    const float* Wih_f   = (const float*)d_in[1];
    const float* Whh_f   = (const float*)d_in[2];
    const float* b_f     = (const float*)d_in[3];
    const float* Wih_b   = (const float*)d_in[4];
    const float* Whh_b   = (const float*)d_in[5];
    const float* b_b     = (const float*)d_in[6];
    const float* W_top   = (const float*)d_in[7];
    const float* b_top   = (const float*)d_in[8];
    const float* start_t = (const float*)d_in[9];
    const float* end_t   = (const float*)d_in[10];
    const float* trans   = (const float*)d_in[11];
    const int*   sent    = (const int*)d_in[12];
    const int*   labels  = (const int*)d_in[13];
    float* out = (float*)d_out;

    float* wsf  = (float*)d_ws;
    float* xp   = wsf;                                   // 2*M*G floats
    float* hbuf = xp   + (size_t)2 * M_ * G_;            // 2*M*H
    float* em   = hbuf + (size_t)2 * M_ * HID_;          // M*L
    float* res  = em   + (size_t)M_ * L_;                // B
    unsigned int* cnt = (unsigned int*)(res + 64);       // NCL counters

    // barrier counters must start at 0 every call (ws is re-poisoned)
    hipMemsetAsync(cnt, 0, NCL * sizeof(unsigned int), stream);

    // 1) input projection GEMM (both dirs)
    k_xproj<<<dim3(2048 / 64, M_ / 64), 256, 0, stream>>>(
        emb, Wih_f, b_f, Wih_b, b_b, sent, xp);

    // 2) whole bidirectional scan, one cooperative launch
    {
        void* args[] = { (void*)&Whh_f, (void*)&Whh_b, (void*)&xp, (void*)&hbuf, (void*)&cnt };
        hipLaunchCooperativeKernel((const void*)k_lstm_scan, dim3(256), dim3(256),
                                   args, 0, stream);
    }

    // 3) emissions
    k_emis<<<(M_ * L_ + 255) / 256, 256, 0, stream>>>(W_top, b_top, hbuf, em);

    // 4) CRF per-sequence
    k_crf<<<B_, 64, 0, stream>>>(start_t, end_t, trans, sent, labels, em, res);

    // 5) final sum
    k_final<<<1, 64, 0, stream>>>(res, out);
}

// Round 3
// 2367.223 us; speedup vs baseline: 3.6140x; 2.3496x over previous
//
#include <hip/hip_runtime.h>
#include <hip/hip_bf16.h>

#define T_    256
#define B_    64
#define EMB_  300
#define HID_  256
#define G_    1024   // 4*HID
#define L_    20
#define M_    (T_*B_)  // 16384

// scan decomposition
#define NCL   16      // clusters = 2 dirs x 8 batch-groups
#define CLB   16      // blocks per cluster (16 units each)
#define BPC   8       // batches per cluster
#define UPB   16      // hidden units per block

// ---------------------------------------------------------------------------
// Kernel 1: xp[dir][t*B+b][g] = dot(emb[sent[t,b]], Wih_dir[g,:]) + b_dir[g]
// ---------------------------------------------------------------------------
__global__ __launch_bounds__(256) void k_xproj(
    const float* __restrict__ emb,
    const float* __restrict__ Wih_f, const float* __restrict__ b_f,
    const float* __restrict__ Wih_b, const float* __restrict__ b_b,
    const int*   __restrict__ sent,
    float* __restrict__ xp)
{
    __shared__ float As[16][68];
    __shared__ float Bs[16][68];
    __shared__ int   words[64];

    const int tid = threadIdx.x;
    const int n0  = blockIdx.x * 64;
    const int m0  = blockIdx.y * 64;
    const int dir = n0 >> 10;
    const int g0  = n0 & 1023;
    const float* __restrict__ Wih  = dir ? Wih_b : Wih_f;
    const float* __restrict__ bias = dir ? b_b   : b_f;

    if (tid < 64) words[tid] = sent[m0 + tid];
    __syncthreads();

    const int r = tid >> 2;
    const int q = tid & 3;
    const float* aptr = emb + (size_t)words[r] * EMB_ + q * 4;
    const float* bptr = Wih + (size_t)(g0 + r) * EMB_ + q * 4;

    const int tx = tid & 15;
    const int ty = tid >> 4;
    float acc[4][4] = {};

    for (int k0 = 0; k0 < 304; k0 += 16) {
        const int k = k0 + q * 4;
        float4 av = make_float4(0.f, 0.f, 0.f, 0.f);
        float4 bv = make_float4(0.f, 0.f, 0.f, 0.f);
        if (k < 300) {
            av = *(const float4*)(aptr + k0);
            bv = *(const float4*)(bptr + k0);
        }
        As[q*4+0][r] = av.x; As[q*4+1][r] = av.y; As[q*4+2][r] = av.z; As[q*4+3][r] = av.w;
        Bs[q*4+0][r] = bv.x; Bs[q*4+1][r] = bv.y; Bs[q*4+2][r] = bv.z; Bs[q*4+3][r] = bv.w;
        __syncthreads();
        #pragma unroll
        for (int kk = 0; kk < 16; ++kk) {
            const float4 a = *(const float4*)&As[kk][ty * 4];
            const float4 b = *(const float4*)&Bs[kk][tx * 4];
            acc[0][0] += a.x*b.x; acc[0][1] += a.x*b.y; acc[0][2] += a.x*b.z; acc[0][3] += a.x*b.w;
            acc[1][0] += a.y*b.x; acc[1][1] += a.y*b.y; acc[1][2] += a.y*b.z; acc[1][3] += a.y*b.w;
            acc[2][0] += a.z*b.x; acc[2][1] += a.z*b.y; acc[2][2] += a.z*b.z; acc[2][3] += a.z*b.w;
            acc[3][0] += a.w*b.x; acc[3][1] += a.w*b.y; acc[3][2] += a.w*b.z; acc[3][3] += a.w*b.w;
        }
        __syncthreads();
    }

    float* out = xp + (size_t)dir * M_ * G_;
    const int g = g0 + tx * 4;
    const float4 bs4 = *(const float4*)(bias + g);
    #pragma unroll
    for (int im = 0; im < 4; ++im) {
        const int m = m0 + ty * 4 + im;
        float4 rv;
        rv.x = acc[im][0] + bs4.x;
        rv.y = acc[im][1] + bs4.y;
        rv.z = acc[im][2] + bs4.z;
        rv.w = acc[im][3] + bs4.w;
        *(float4*)(out + (size_t)m * G_ + g) = rv;
    }
}

// ---------------------------------------------------------------------------
// Kernel 2: full bidirectional LSTM scan, one cooperative launch.
// 256 blocks = 16 clusters x 16 blocks. Whh pinned in VGPRs
// (launch_bounds(256,1) -> up to 512 VGPR/thread so the 64-VGPR wv[] stays
// resident; R1's launch_bounds(256) made the allocator sink the weight loads
// into the loop = L2 streaming every step).
// Cross-block h exchange: relaxed agent-scope atomic stores (write-through,
// no wbl2), epoch flags, relaxed agent-scope atomic reloads. NO threadfence.
// ---------------------------------------------------------------------------
__global__ __launch_bounds__(256, 1) void k_lstm_scan(
    const float* __restrict__ Whh_f, const float* __restrict__ Whh_b,
    const float* __restrict__ xp, float* __restrict__ hbuf,
    int* __restrict__ flags)
{
    const int cl   = blockIdx.x >> 4;       // 0..15
    const int rank = blockIdx.x & 15;       // unit-group within cluster
    const int dir  = cl >> 3;
    const int bg   = cl & 7;
    const int b0   = bg * BPC;
    const int u0   = rank * UPB;
    const int tid  = threadIdx.x;
    const int lane = tid & 63;
    const int wave = tid >> 6;      // == gate index (i,f,g,o)
    const int r16  = lane & 15;     // unit within block
    const int kq   = lane >> 4;     // k-quarter (64 k each)

    const float* __restrict__ Whh = dir ? Whh_b : Whh_f;
    const float* __restrict__ xpd = xp + (size_t)dir * M_ * G_;
    float* __restrict__ hdir = hbuf + (size_t)dir * M_ * HID_;
    int* __restrict__ myflags = flags + cl * 32;

    __shared__ float hs[BPC][272];     // h-tile, kq-slices at stride 68
    __shared__ float Cg[64][9];        // gate pre-activations [g*16+u][b]
    __shared__ float cs[BPC][UPB + 1]; // cell state

    for (int i = tid; i < BPC * 272; i += 256) ((float*)hs)[i] = 0.f;
    if (tid < BPC * (UPB + 1)) ((float*)cs)[tid] = 0.f;

    // permanent register-resident Whh slice: row (wave*256 + u0 + r16),
    // k in [64*kq, 64*kq+64)
    float4 wv[16];
    {
        const float* wrow = Whh + (size_t)(wave * HID_ + u0 + r16) * HID_ + kq * 64;
        #pragma unroll
        for (int i = 0; i < 16; ++i) wv[i] = ((const float4*)wrow)[i];
    }
    __syncthreads();

    const int eu = tid & 15;           // epilogue unit
    const int eb = (tid >> 4) & 7;     // epilogue batch

    for (int t = 0; t < T_; ++t) {
        const int t_eff = dir ? (T_ - 1 - t) : t;

        // prefetch this step's xp gates (latency hides under the MAC loop)
        float x0 = 0.f, x1 = 0.f, x2 = 0.f, x3 = 0.f;
        if (tid < 128) {
            const float* xrow = xpd + ((size_t)t_eff * B_ + (b0 + eb)) * G_ + (u0 + eu);
            x0 = xrow[0]; x1 = xrow[HID_]; x2 = xrow[2 * HID_]; x3 = xrow[3 * HID_];
        }

        // gate GEMM: acc[b][row] = sum_k Whh[row][k] * h_prev[b][k]
        #pragma unroll 4
        for (int b = 0; b < BPC; ++b) {
            const float4* hv = (const float4*)&hs[b][kq * 68];
            float acc = 0.f;
            #pragma unroll
            for (int i = 0; i < 16; ++i) {
                const float4 h4 = hv[i];
                const float4 w4 = wv[i];
                acc += w4.x * h4.x + w4.y * h4.y + w4.z * h4.z + w4.w * h4.w;
            }
            acc += __shfl_xor(acc, 16);
            acc += __shfl_xor(acc, 32);
            if (kq == 0) Cg[wave * 16 + r16][b] = acc;
        }
        __syncthreads();

        if (tid < 128) {
            const float gi = Cg[0 * 16 + eu][eb] + x0;
            const float gf = Cg[1 * 16 + eu][eb] + x1;
            const float gg = Cg[2 * 16 + eu][eb] + x2;
            const float go = Cg[3 * 16 + eu][eb] + x3;
            const float i_ = 1.f / (1.f + __expf(-gi));
            const float f_ = 1.f / (1.f + __expf(-gf));
            const float g_ = tanhf(gg);
            const float o_ = 1.f / (1.f + __expf(-go));
            const float cn = f_ * cs[eb][eu] + i_ * g_;
            const float hn = o_ * tanhf(cn);
            cs[eb][eu] = cn;
            // agent-scope write-through store: visible at coherent point,
            // no L2 writeback fence needed
            __hip_atomic_store(
                &hdir[((size_t)t_eff * B_ + (b0 + eb)) * HID_ + (u0 + eu)],
                hn, __ATOMIC_RELAXED, __HIP_MEMORY_SCOPE_AGENT);
        }
        __syncthreads();   // drains vmcnt: all h stores acked at coherent point

        if (t == T_ - 1) break;

        // epoch-flag cluster barrier (no fences, no RMW contention)
        if (tid == 0)
            __hip_atomic_store(&myflags[rank], t + 1,
                               __ATOMIC_RELAXED, __HIP_MEMORY_SCOPE_AGENT);
        if (tid < 64) {
            while (true) {
                int v = (tid < CLB)
                    ? __hip_atomic_load(&myflags[tid], __ATOMIC_RELAXED,
                                        __HIP_MEMORY_SCOPE_AGENT)
                    : 0x7FFFFFFF;
                if (__ballot(v <= t) == 0ULL) break;
                __builtin_amdgcn_s_sleep(1);
            }
        }
        __syncthreads();

        // reload full h-tile (agent-scope loads bypass stale L1/L2)
        {
            const float* hsrc = hdir + (size_t)t_eff * B_ * HID_ + (size_t)b0 * HID_;
            #pragma unroll
            for (int i = 0; i < 8; ++i) {
                const int idx = i * 256 + tid;     // 0..2047 floats
                const int b = idx >> 8, k = idx & 255;
                const float v = __hip_atomic_load(hsrc + (size_t)b * HID_ + k,
                                                  __ATOMIC_RELAXED,
                                                  __HIP_MEMORY_SCOPE_AGENT);
                hs[b][(k >> 6) * 68 + (k & 63)] = v;
            }
        }
        __syncthreads();
    }
}

// ---------------------------------------------------------------------------
// Kernel 3: emissions[t,b,l] = b_top[l] + h_f . W_top[l,:256] + h_b . W_top[l,256:]
// ---------------------------------------------------------------------------
__global__ __launch_bounds__(256) void k_emis(
    const float* __restrict__ Wt, const float* __restrict__ bt,
    const float* __restrict__ hbuf, float* __restrict__ em)
{
    const int gid = blockIdx.x * 256 + threadIdx.x;
    if (gid >= M_ * L_) return;
    const int m = gid / L_;
    const int l = gid - m * L_;
    const float4* hf  = (const float4*)(hbuf + (size_t)m * HID_);
    const float4* hbk = (const float4*)(hbuf + (size_t)M_ * HID_ + (size_t)m * HID_);
    const float4* w0  = (const float4*)(Wt + (size_t)l * 2 * HID_);
    const float4* w1  = w0 + HID_ / 4;
    float acc = bt[l];
    #pragma unroll 4
    for (int k = 0; k < HID_ / 4; ++k) {
        float4 h = hf[k],  w = w0[k];
        acc += h.x*w.x + h.y*w.y + h.z*w.z + h.w*w.w;
        h = hbk[k]; w = w1[k];
        acc += h.x*w.x + h.y*w.y + h.z*w.z + h.w*w.w;
    }
    em[gid] = acc;
}

// ---------------------------------------------------------------------------
// Kernel 4: CRF per-sequence forward + gold score. One block per b.
// ---------------------------------------------------------------------------
__global__ __launch_bounds__(64) void k_crf(
    const float* __restrict__ start_t, const float* __restrict__ end_t,
    const float* __restrict__ trans,
    const int* __restrict__ sent, const int* __restrict__ labels,
    const float* __restrict__ em, float* __restrict__ res)
{
    const int b = blockIdx.x;
    const int tid = threadIdx.x;
    __shared__ float tr[L_ * L_];
    __shared__ float alpha[2][L_];
    __shared__ float red[64];
    __shared__ int   redi[64];
    __shared__ float sdenom;

    for (int i = tid; i < L_ * L_; i += 64) tr[i] = trans[i];
    if (tid < L_) alpha[0][tid] = start_t[tid] + em[b * L_ + tid];
    __syncthreads();

    int p = 0;
    for (int t = 1; t < T_; ++t) {
        float val = 0.f;
        if (tid < L_) {
            if (sent[t * B_ + b] != 0) {
                float mx = -1e30f;
                #pragma unroll
                for (int i = 0; i < L_; ++i) mx = fmaxf(mx, alpha[p][i] + tr[i * L_ + tid]);
                float s = 0.f;
                #pragma unroll
                for (int i = 0; i < L_; ++i) s += __expf(alpha[p][i] + tr[i * L_ + tid] - mx);
                val = mx + __logf(s) + em[(t * B_ + b) * L_ + tid];
            } else {
                val = alpha[p][tid];
            }
        }
        if (tid < L_) alpha[1 - p][tid] = val;
        __syncthreads();
        p ^= 1;
    }

    if (tid == 0) {
        float mx = -1e30f;
        for (int j = 0; j < L_; ++j) mx = fmaxf(mx, alpha[p][j] + end_t[j]);
        float s = 0.f;
        for (int j = 0; j < L_; ++j) s += __expf(alpha[p][j] + end_t[j] - mx);
        sdenom = mx + __logf(s);
    }

    float loc = 0.f;
    int   cnt = 0;
    for (int t = tid; t < T_; t += 64) {
        const int masked = (sent[t * B_ + b] != 0);
        cnt += masked;
        if (t >= 1 && masked) {
            const int tp = labels[(t - 1) * B_ + b];
            const int tc = labels[t * B_ + b];
            loc += tr[tp * L_ + tc] + em[(t * B_ + b) * L_ + tc];
        }
    }
    red[tid] = loc; redi[tid] = cnt;
    __syncthreads();
    if (tid == 0) {
        float s = 0.f; int c = 0;
        for (int i = 0; i < 64; ++i) { s += red[i]; c += redi[i]; }
        const int tag0 = labels[b];
        const int seq_end = c - 1;
        const int last = labels[seq_end * B_ + b];
        const float score = start_t[tag0] + em[b * L_ + tag0] + s + end_t[last];
        res[b] = score - sdenom;
    }
}

// ---------------------------------------------------------------------------
// Kernel 5: out[0] = -sum_b res[b]
// ---------------------------------------------------------------------------
__global__ __launch_bounds__(64) void k_final(const float* __restrict__ res,
                                              float* __restrict__ out)
{
    __shared__ float red[64];
    red[threadIdx.x] = res[threadIdx.x];
    __syncthreads();
    if (threadIdx.x == 0) {
        float s = 0.f;
        for (int i = 0; i < 64; ++i) s += red[i];
        out[0] = -s;
    }
}

// ---------------------------------------------------------------------------
extern "C" void kernel_launch(void* const* d_in, const int* in_sizes, int n_in,
                              void* d_out, int out_size, void* d_ws, size_t ws_size,
                              hipStream_t stream)
{
    const float* emb     = (const float*)d_in[0];
    const float* Wih_f   = (const float*)d_in[1];
    const float* Whh_f   = (const float*)d_in[2];
    const float* b_f     = (const float*)d_in[3];
    const float* Wih_b   = (const float*)d_in[4];
    const float* Whh_b   = (const float*)d_in[5];
    const float* b_b     = (const float*)d_in[6];
    const float* W_top   = (const float*)d_in[7];
    const float* b_top   = (const float*)d_in[8];
    const float* start_t = (const float*)d_in[9];
    const float* end_t   = (const float*)d_in[10];
    const float* trans   = (const float*)d_in[11];
    const int*   sent    = (const int*)d_in[12];
    const int*   labels  = (const int*)d_in[13];
    float* out = (float*)d_out;

    float* wsf  = (float*)d_ws;
    float* xp   = wsf;                                   // 2*M*G floats
    float* hbuf = xp   + (size_t)2 * M_ * G_;            // 2*M*H
    float* em   = hbuf + (size_t)2 * M_ * HID_;          // M*L
    float* res  = em   + (size_t)M_ * L_;                // B
    int*   flags = (int*)(res + 64);                     // NCL*32 ints

    // epoch flags must start at 0 every call (ws is re-poisoned to 0xAA)
    hipMemsetAsync(flags, 0, NCL * 32 * sizeof(int), stream);

    // 1) input projection GEMM (both dirs)
    k_xproj<<<dim3(2048 / 64, M_ / 64), 256, 0, stream>>>(
        emb, Wih_f, b_f, Wih_b, b_b, sent, xp);

    // 2) whole bidirectional scan, one cooperative launch
    {
        void* args[] = { (void*)&Whh_f, (void*)&Whh_b, (void*)&xp, (void*)&hbuf, (void*)&flags };
        hipLaunchCooperativeKernel((const void*)k_lstm_scan, dim3(256), dim3(256),
                                   args, 0, stream);
    }

    // 3) emissions
    k_emis<<<(M_ * L_ + 255) / 256, 256, 0, stream>>>(W_top, b_top, hbuf, em);

    // 4) CRF per-sequence
    k_crf<<<B_, 64, 0, stream>>>(start_t, end_t, trans, sent, labels, em, res);

    // 5) final sum
    k_final<<<1, 64, 0, stream>>>(res, out);
}

// Round 4
// 2044.379 us; speedup vs baseline: 4.1847x; 1.1579x over previous
//
#include <hip/hip_runtime.h>
#include <hip/hip_bf16.h>

#define T_    256
#define B_    64
#define EMB_  300
#define HID_  256
#define G_    1024   // 4*HID
#define L_    20
#define M_    (T_*B_)  // 16384

// scan decomposition: 32 clusters = 2 dirs x 16 batch-groups; 8 blocks/cluster
#define NCL   32
#define CLB   8
#define BPC   4      // batches per cluster
#define UPB   32     // hidden units per block

typedef float f32x4 __attribute__((ext_vector_type(4)));

// ---------------------------------------------------------------------------
// Kernel 1: xp[dir][t*B+b][g] = dot(emb[sent[t,b]], Wih_dir[g,:]) + b_dir[g]
// ---------------------------------------------------------------------------
__global__ __launch_bounds__(256) void k_xproj(
    const float* __restrict__ emb,
    const float* __restrict__ Wih_f, const float* __restrict__ b_f,
    const float* __restrict__ Wih_b, const float* __restrict__ b_b,
    const int*   __restrict__ sent,
    float* __restrict__ xp)
{
    __shared__ float As[16][68];
    __shared__ float Bs[16][68];
    __shared__ int   words[64];

    const int tid = threadIdx.x;
    const int n0  = blockIdx.x * 64;
    const int m0  = blockIdx.y * 64;
    const int dir = n0 >> 10;
    const int g0  = n0 & 1023;
    const float* __restrict__ Wih  = dir ? Wih_b : Wih_f;
    const float* __restrict__ bias = dir ? b_b   : b_f;

    if (tid < 64) words[tid] = sent[m0 + tid];
    __syncthreads();

    const int r = tid >> 2;
    const int q = tid & 3;
    const float* aptr = emb + (size_t)words[r] * EMB_ + q * 4;
    const float* bptr = Wih + (size_t)(g0 + r) * EMB_ + q * 4;

    const int tx = tid & 15;
    const int ty = tid >> 4;
    float acc[4][4] = {};

    for (int k0 = 0; k0 < 304; k0 += 16) {
        const int k = k0 + q * 4;
        float4 av = make_float4(0.f, 0.f, 0.f, 0.f);
        float4 bv = make_float4(0.f, 0.f, 0.f, 0.f);
        if (k < 300) {
            av = *(const float4*)(aptr + k0);
            bv = *(const float4*)(bptr + k0);
        }
        As[q*4+0][r] = av.x; As[q*4+1][r] = av.y; As[q*4+2][r] = av.z; As[q*4+3][r] = av.w;
        Bs[q*4+0][r] = bv.x; Bs[q*4+1][r] = bv.y; Bs[q*4+2][r] = bv.z; Bs[q*4+3][r] = bv.w;
        __syncthreads();
        #pragma unroll
        for (int kk = 0; kk < 16; ++kk) {
            const float4 a = *(const float4*)&As[kk][ty * 4];
            const float4 b = *(const float4*)&Bs[kk][tx * 4];
            acc[0][0] += a.x*b.x; acc[0][1] += a.x*b.y; acc[0][2] += a.x*b.z; acc[0][3] += a.x*b.w;
            acc[1][0] += a.y*b.x; acc[1][1] += a.y*b.y; acc[1][2] += a.y*b.z; acc[1][3] += a.y*b.w;
            acc[2][0] += a.z*b.x; acc[2][1] += a.z*b.y; acc[2][2] += a.z*b.z; acc[2][3] += a.z*b.w;
            acc[3][0] += a.w*b.x; acc[3][1] += a.w*b.y; acc[3][2] += a.w*b.z; acc[3][3] += a.w*b.w;
        }
        __syncthreads();
    }

    float* out = xp + (size_t)dir * M_ * G_;
    const int g = g0 + tx * 4;
    const float4 bs4 = *(const float4*)(bias + g);
    #pragma unroll
    for (int im = 0; im < 4; ++im) {
        const int m = m0 + ty * 4 + im;
        float4 rv;
        rv.x = acc[im][0] + bs4.x;
        rv.y = acc[im][1] + bs4.y;
        rv.z = acc[im][2] + bs4.z;
        rv.w = acc[im][3] + bs4.w;
        *(float4*)(out + (size_t)m * G_ + g) = rv;
    }
}

// ---------------------------------------------------------------------------
// Kernel 2: full bidirectional LSTM scan, one cooperative launch.
// 256 blocks = 32 clusters x 8 blocks. Block owns 32 units x 4 gates x
// 4 batches. Whh slice pinned in VGPRs: 32 x f32x4 = 128 VGPR/thread,
// 2 MB machine-wide = all of Whh. The empty asm("" : "+v") inside the
// t-loop FORCES residency (R2's launch_bounds(256,1) alone did not:
// allocator chose 60 VGPRs and re-streamed weights from L2 every step).
// Cross-block h exchange: relaxed agent-scope stores -> epoch flags ->
// relaxed agent-scope reloads. No fences, no L2 writebacks.
// ---------------------------------------------------------------------------
__global__ __launch_bounds__(256, 1) void k_lstm_scan(
    const float* __restrict__ Whh_f, const float* __restrict__ Whh_b,
    const float* __restrict__ xp, float* __restrict__ hbuf,
    int* __restrict__ flags)
{
    const int rank = blockIdx.x & 7;        // block within cluster
    const int cl   = blockIdx.x >> 3;       // 0..31
    const int dir  = cl >> 4;
    const int bg   = cl & 15;
    const int b0   = bg * BPC;
    const int u0   = rank * UPB;
    const int tid  = threadIdx.x;
    const int lane = tid & 63;
    const int g    = tid >> 6;      // wave == gate index (i,f,g,o)
    const int r32  = lane & 31;     // unit within block
    const int kh   = lane >> 5;     // k-half (128 k each)

    const float* __restrict__ Whh = dir ? Whh_b : Whh_f;
    const float* __restrict__ xpd = xp + (size_t)dir * M_ * G_;
    float* __restrict__ hdir = hbuf + (size_t)dir * M_ * HID_;
    int* __restrict__ myflags = flags + cl * 16;

    __shared__ float hs[BPC][264];       // h-tile; k-halves at stride 132
    __shared__ float Cg[4][UPB][BPC+1];  // gate pre-activations [g][u][b]
    __shared__ float cs[BPC][UPB + 1];   // cell state

    for (int i = tid; i < BPC * 264; i += 256) ((float*)hs)[i] = 0.f;
    if (tid < BPC * (UPB + 1)) ((float*)cs)[tid] = 0.f;

    // register-resident Whh slice: row (g*256 + u0 + r32), k in [128kh,128kh+128)
    f32x4 wv[32];
    {
        const f32x4* wrow = (const f32x4*)(Whh + (size_t)(g * HID_ + u0 + r32) * HID_ + kh * 128);
        #pragma unroll
        for (int i = 0; i < 32; ++i) wv[i] = wrow[i];
    }
    __syncthreads();

    const int eu = tid & 31;           // epilogue unit
    const int eb = tid >> 5;           // epilogue batch (valid for tid<128)

    for (int t = 0; t < T_; ++t) {
        const int t_eff = dir ? (T_ - 1 - t) : t;

        // force the 128 weight VGPRs live here -> loads cannot sink into loop
        #pragma unroll
        for (int i = 0; i < 32; ++i) asm volatile("" : "+v"(wv[i]));

        // prefetch this step's xp gates (hides under the MAC loop)
        float x0 = 0.f, x1 = 0.f, x2 = 0.f, x3 = 0.f;
        if (tid < 128) {
            const float* xrow = xpd + ((size_t)t_eff * B_ + (b0 + eb)) * G_ + (u0 + eu);
            x0 = xrow[0]; x1 = xrow[HID_]; x2 = xrow[2 * HID_]; x3 = xrow[3 * HID_];
        }

        // gate GEMM: Cg[g][u][b] = sum_k Whh[g*256+u0+u][k] * h_prev[b][k]
        #pragma unroll
        for (int b = 0; b < BPC; ++b) {
            const f32x4* hv = (const f32x4*)&hs[b][kh * 132];
            float acc = 0.f;
            #pragma unroll
            for (int i = 0; i < 32; ++i) {
                const f32x4 w4 = wv[i];
                const f32x4 h4 = hv[i];
                acc += w4.x * h4.x + w4.y * h4.y + w4.z * h4.z + w4.w * h4.w;
            }
            acc += __shfl_xor(acc, 32);
            if (kh == 0) Cg[g][r32][b] = acc;
        }
        __syncthreads();

        if (tid < 128) {
            const float gi = Cg[0][eu][eb] + x0;
            const float gf = Cg[1][eu][eb] + x1;
            const float gg = Cg[2][eu][eb] + x2;
            const float go = Cg[3][eu][eb] + x3;
            const float i_ = 1.f / (1.f + __expf(-gi));
            const float f_ = 1.f / (1.f + __expf(-gf));
            const float g_ = tanhf(gg);
            const float o_ = 1.f / (1.f + __expf(-go));
            const float cn = f_ * cs[eb][eu] + i_ * g_;
            const float hn = o_ * tanhf(cn);
            cs[eb][eu] = cn;
            // agent-scope write-through store (visible at coherent point)
            __hip_atomic_store(
                &hdir[((size_t)t_eff * B_ + (b0 + eb)) * HID_ + (u0 + eu)],
                hn, __ATOMIC_RELAXED, __HIP_MEMORY_SCOPE_AGENT);
        }
        __syncthreads();   // vmcnt(0) before s_barrier: all h stores acked

        if (t == T_ - 1) break;

        // epoch-flag cluster barrier (8 peers, no fences, no RMW)
        if (tid == 0)
            __hip_atomic_store(&myflags[rank], t + 1,
                               __ATOMIC_RELAXED, __HIP_MEMORY_SCOPE_AGENT);
        if (tid < 64) {
            while (true) {
                int v = (tid < CLB)
                    ? __hip_atomic_load(&myflags[tid], __ATOMIC_RELAXED,
                                        __HIP_MEMORY_SCOPE_AGENT)
                    : 0x7FFFFFFF;
                if (__ballot(v <= t) == 0ULL) break;
                __builtin_amdgcn_s_sleep(1);
            }
        }
        __syncthreads();

        // reload cluster h-tile (4 batches x 256) via agent-scope loads
        {
            const float* hsrc = hdir + ((size_t)t_eff * B_ + b0) * HID_;
            #pragma unroll
            for (int i = 0; i < 4; ++i) {
                const int idx = i * 256 + tid;   // 0..1023
                const int b = idx >> 8, k = idx & 255;
                const float v = __hip_atomic_load(hsrc + (size_t)b * HID_ + k,
                                                  __ATOMIC_RELAXED,
                                                  __HIP_MEMORY_SCOPE_AGENT);
                hs[b][(k >> 7) * 132 + (k & 127)] = v;
            }
        }
        __syncthreads();
    }
}

// ---------------------------------------------------------------------------
// Kernel 3: emissions[t,b,l] = b_top[l] + h_f . W_top[l,:256] + h_b . W_top[l,256:]
// ---------------------------------------------------------------------------
__global__ __launch_bounds__(256) void k_emis(
    const float* __restrict__ Wt, const float* __restrict__ bt,
    const float* __restrict__ hbuf, float* __restrict__ em)
{
    const int gid = blockIdx.x * 256 + threadIdx.x;
    if (gid >= M_ * L_) return;
    const int m = gid / L_;
    const int l = gid - m * L_;
    const float4* hf  = (const float4*)(hbuf + (size_t)m * HID_);
    const float4* hbk = (const float4*)(hbuf + (size_t)M_ * HID_ + (size_t)m * HID_);
    const float4* w0  = (const float4*)(Wt + (size_t)l * 2 * HID_);
    const float4* w1  = w0 + HID_ / 4;
    float acc = bt[l];
    #pragma unroll 4
    for (int k = 0; k < HID_ / 4; ++k) {
        float4 h = hf[k],  w = w0[k];
        acc += h.x*w.x + h.y*w.y + h.z*w.z + h.w*w.w;
        h = hbk[k]; w = w1[k];
        acc += h.x*w.x + h.y*w.y + h.z*w.z + h.w*w.w;
    }
    em[gid] = acc;
}

// ---------------------------------------------------------------------------
// Kernel 4: CRF per-sequence forward + gold score. One block per b.
// em/sent rows for t+1 prefetched while computing step t.
// ---------------------------------------------------------------------------
__global__ __launch_bounds__(64) void k_crf(
    const float* __restrict__ start_t, const float* __restrict__ end_t,
    const float* __restrict__ trans,
    const int* __restrict__ sent, const int* __restrict__ labels,
    const float* __restrict__ em, float* __restrict__ res)
{
    const int b = blockIdx.x;
    const int tid = threadIdx.x;
    __shared__ float tr[L_ * L_];
    __shared__ float alpha[2][L_];
    __shared__ float red[64];
    __shared__ int   redi[64];
    __shared__ float sdenom;

    for (int i = tid; i < L_ * L_; i += 64) tr[i] = trans[i];
    if (tid < L_) alpha[0][tid] = start_t[tid] + em[b * L_ + tid];
    __syncthreads();

    float pre_em = (tid < L_) ? em[(B_ + b) * L_ + tid] : 0.f;
    int   pre_m  = sent[B_ + b];

    int p = 0;
    for (int t = 1; t < T_; ++t) {
        const float emt = pre_em;
        const int   mt  = pre_m;
        if (t + 1 < T_) {
            if (tid < L_) pre_em = em[((t + 1) * B_ + b) * L_ + tid];
            pre_m = sent[(t + 1) * B_ + b];
        }
        float val = 0.f;
        if (tid < L_) {
            if (mt != 0) {
                float mx = -1e30f;
                #pragma unroll
                for (int i = 0; i < L_; ++i) mx = fmaxf(mx, alpha[p][i] + tr[i * L_ + tid]);
                float s = 0.f;
                #pragma unroll
                for (int i = 0; i < L_; ++i) s += __expf(alpha[p][i] + tr[i * L_ + tid] - mx);
                val = mx + __logf(s) + emt;
            } else {
                val = alpha[p][tid];
            }
        }
        if (tid < L_) alpha[1 - p][tid] = val;
        __syncthreads();
        p ^= 1;
    }

    if (tid == 0) {
        float mx = -1e30f;
        for (int j = 0; j < L_; ++j) mx = fmaxf(mx, alpha[p][j] + end_t[j]);
        float s = 0.f;
        for (int j = 0; j < L_; ++j) s += __expf(alpha[p][j] + end_t[j] - mx);
        sdenom = mx + __logf(s);
    }

    float loc = 0.f;
    int   cnt = 0;
    for (int t = tid; t < T_; t += 64) {
        const int masked = (sent[t * B_ + b] != 0);
        cnt += masked;
        if (t >= 1 && masked) {
            const int tp = labels[(t - 1) * B_ + b];
            const int tc = labels[t * B_ + b];
            loc += tr[tp * L_ + tc] + em[(t * B_ + b) * L_ + tc];
        }
    }
    red[tid] = loc; redi[tid] = cnt;
    __syncthreads();
    if (tid == 0) {
        float s = 0.f; int c = 0;
        for (int i = 0; i < 64; ++i) { s += red[i]; c += redi[i]; }
        const int tag0 = labels[b];
        const int seq_end = c - 1;
        const int last = labels[seq_end * B_ + b];
        const float score = start_t[tag0] + em[b * L_ + tag0] + s + end_t[last];
        res[b] = score - sdenom;
    }
}

// ---------------------------------------------------------------------------
// Kernel 5: out[0] = -sum_b res[b]
// ---------------------------------------------------------------------------
__global__ __launch_bounds__(64) void k_final(const float* __restrict__ res,
                                              float* __restrict__ out)
{
    __shared__ float red[64];
    red[threadIdx.x] = res[threadIdx.x];
    __syncthreads();
    if (threadIdx.x == 0) {
        float s = 0.f;
        for (int i = 0; i < 64; ++i) s += red[i];
        out[0] = -s;
    }
}

// ---------------------------------------------------------------------------
extern "C" void kernel_launch(void* const* d_in, const int* in_sizes, int n_in,
                              void* d_out, int out_size, void* d_ws, size_t ws_size,
                              hipStream_t stream)
{
    const float* emb     = (const float*)d_in[0];
    const float* Wih_f   = (const float*)d_in[1];
    const float* Whh_f   = (const float*)d_in[2];
    const float* b_f     = (const float*)d_in[3];
    const float* Wih_b   = (const float*)d_in[4];
    const float* Whh_b   = (const float*)d_in[5];
    const float* b_b     = (const float*)d_in[6];
    const float* W_top   = (const float*)d_in[7];
    const float* b_top   = (const float*)d_in[8];
    const float* start_t = (const float*)d_in[9];
    const float* end_t   = (const float*)d_in[10];
    const float* trans   = (const float*)d_in[11];
    const int*   sent    = (const int*)d_in[12];
    const int*   labels  = (const int*)d_in[13];
    float* out = (float*)d_out;

    float* wsf  = (float*)d_ws;
    float* xp   = wsf;                                   // 2*M*G floats
    float* hbuf = xp   + (size_t)2 * M_ * G_;            // 2*M*H
    float* em   = hbuf + (size_t)2 * M_ * HID_;          // M*L
    float* res  = em   + (size_t)M_ * L_;                // B
    int*   flags = (int*)(res + 64);                     // NCL*16 ints

    // epoch flags must start at 0 every call (ws is re-poisoned to 0xAA)
    hipMemsetAsync(flags, 0, NCL * 16 * sizeof(int), stream);

    // 1) input projection GEMM (both dirs)
    k_xproj<<<dim3(2048 / 64, M_ / 64), 256, 0, stream>>>(
        emb, Wih_f, b_f, Wih_b, b_b, sent, xp);

    // 2) whole bidirectional scan, one cooperative launch
    {
        void* args[] = { (void*)&Whh_f, (void*)&Whh_b, (void*)&xp, (void*)&hbuf, (void*)&flags };
        hipLaunchCooperativeKernel((const void*)k_lstm_scan, dim3(256), dim3(256),
                                   args, 0, stream);
    }

    // 3) emissions
    k_emis<<<(M_ * L_ + 255) / 256, 256, 0, stream>>>(W_top, b_top, hbuf, em);

    // 4) CRF per-sequence
    k_crf<<<B_, 64, 0, stream>>>(start_t, end_t, trans, sent, labels, em, res);

    // 5) final sum
    k_final<<<1, 64, 0, stream>>>(res, out);
}

// Round 5
// 1845.701 us; speedup vs baseline: 4.6351x; 1.1076x over previous
//
#include <hip/hip_runtime.h>
#include <hip/hip_bf16.h>

#define T_    256
#define B_    64
#define EMB_  300
#define HID_  256
#define G_    1024   // 4*HID
#define L_    20
#define M_    (T_*B_)  // 16384

// scan decomposition: 32 clusters = 2 dirs x 16 batch-groups; 8 blocks/cluster
#define NCL   32
#define CLB   8
#define BPC   4      // batches per cluster
#define UPB   32     // hidden units per block

typedef float f32x4 __attribute__((ext_vector_type(4)));
typedef unsigned long long u64;

// ---------------------------------------------------------------------------
// Kernel 1: xp[dir][t*B+b][g] = dot(emb[sent[t,b]], Wih_dir[g,:]) + b_dir[g]
// ---------------------------------------------------------------------------
__global__ __launch_bounds__(256) void k_xproj(
    const float* __restrict__ emb,
    const float* __restrict__ Wih_f, const float* __restrict__ b_f,
    const float* __restrict__ Wih_b, const float* __restrict__ b_b,
    const int*   __restrict__ sent,
    float* __restrict__ xp)
{
    __shared__ float As[16][68];
    __shared__ float Bs[16][68];
    __shared__ int   words[64];

    const int tid = threadIdx.x;
    const int n0  = blockIdx.x * 64;
    const int m0  = blockIdx.y * 64;
    const int dir = n0 >> 10;
    const int g0  = n0 & 1023;
    const float* __restrict__ Wih  = dir ? Wih_b : Wih_f;
    const float* __restrict__ bias = dir ? b_b   : b_f;

    if (tid < 64) words[tid] = sent[m0 + tid];
    __syncthreads();

    const int r = tid >> 2;
    const int q = tid & 3;
    const float* aptr = emb + (size_t)words[r] * EMB_ + q * 4;
    const float* bptr = Wih + (size_t)(g0 + r) * EMB_ + q * 4;

    const int tx = tid & 15;
    const int ty = tid >> 4;
    float acc[4][4] = {};

    for (int k0 = 0; k0 < 304; k0 += 16) {
        const int k = k0 + q * 4;
        float4 av = make_float4(0.f, 0.f, 0.f, 0.f);
        float4 bv = make_float4(0.f, 0.f, 0.f, 0.f);
        if (k < 300) {
            av = *(const float4*)(aptr + k0);
            bv = *(const float4*)(bptr + k0);
        }
        As[q*4+0][r] = av.x; As[q*4+1][r] = av.y; As[q*4+2][r] = av.z; As[q*4+3][r] = av.w;
        Bs[q*4+0][r] = bv.x; Bs[q*4+1][r] = bv.y; Bs[q*4+2][r] = bv.z; Bs[q*4+3][r] = bv.w;
        __syncthreads();
        #pragma unroll
        for (int kk = 0; kk < 16; ++kk) {
            const float4 a = *(const float4*)&As[kk][ty * 4];
            const float4 b = *(const float4*)&Bs[kk][tx * 4];
            acc[0][0] += a.x*b.x; acc[0][1] += a.x*b.y; acc[0][2] += a.x*b.z; acc[0][3] += a.x*b.w;
            acc[1][0] += a.y*b.x; acc[1][1] += a.y*b.y; acc[1][2] += a.y*b.z; acc[1][3] += a.y*b.w;
            acc[2][0] += a.z*b.x; acc[2][1] += a.z*b.y; acc[2][2] += a.z*b.z; acc[2][3] += a.z*b.w;
            acc[3][0] += a.w*b.x; acc[3][1] += a.w*b.y; acc[3][2] += a.w*b.z; acc[3][3] += a.w*b.w;
        }
        __syncthreads();
    }

    float* out = xp + (size_t)dir * M_ * G_;
    const int g = g0 + tx * 4;
    const float4 bs4 = *(const float4*)(bias + g);
    #pragma unroll
    for (int im = 0; im < 4; ++im) {
        const int m = m0 + ty * 4 + im;
        float4 rv;
        rv.x = acc[im][0] + bs4.x;
        rv.y = acc[im][1] + bs4.y;
        rv.z = acc[im][2] + bs4.z;
        rv.w = acc[im][3] + bs4.w;
        *(float4*)(out + (size_t)m * G_ + g) = rv;
    }
}

// ---------------------------------------------------------------------------
// Kernel 2: full bidirectional LSTM scan, one cooperative launch.
// 256 blocks = 32 clusters x 8 blocks; block owns 32 units x 4 gates x
// 4 batches; Whh slice held via asm-pin (R4: VGPR 88 + AGPR park, works).
// NEW (R4->R5): exchange = epoch-tagged packed h words. Producer does ONE
// relaxed agent-scope 8B store (tag<<32 | f32); consumers POLL THE DATA
// directly until tag==t. No flag array, no vmcnt-drain barrier, no flag RTT:
// 3 L3 round-trips/step -> 1. Tags 1..255; 0xAA ws-poison never matches.
// ---------------------------------------------------------------------------
__global__ __launch_bounds__(256, 1) void k_lstm_scan(
    const float* __restrict__ Whh_f, const float* __restrict__ Whh_b,
    const float* __restrict__ xp, float* __restrict__ hbuf,
    u64* __restrict__ xch)
{
    const int rank = blockIdx.x & 7;        // block within cluster
    const int cl   = blockIdx.x >> 3;       // 0..31
    const int dir  = cl >> 4;
    const int bg   = cl & 15;
    const int b0   = bg * BPC;
    const int u0   = rank * UPB;
    const int tid  = threadIdx.x;
    const int lane = tid & 63;
    const int g    = tid >> 6;      // wave == gate index (i,f,g,o)
    const int r32  = lane & 31;     // unit within block
    const int kh   = lane >> 5;     // k-half (128 k each)

    const float* __restrict__ Whh = dir ? Whh_b : Whh_f;
    const float* __restrict__ xpd = xp + (size_t)dir * M_ * G_;
    float* __restrict__ hdir = hbuf + (size_t)dir * M_ * HID_;
    u64* __restrict__ xc = xch + ((size_t)dir * B_ + b0) * HID_;  // cluster slice

    __shared__ float hs[BPC][264];       // h-tile; k-halves at stride 132
    __shared__ float Cg[4][UPB][BPC+1];  // gate pre-activations [g][u][b]
    __shared__ float cs[BPC][UPB + 1];   // cell state

    for (int i = tid; i < BPC * 264; i += 256) ((float*)hs)[i] = 0.f;
    if (tid < BPC * (UPB + 1)) ((float*)cs)[tid] = 0.f;

    // register-resident Whh slice: row (g*256 + u0 + r32), k in [128kh,128kh+128)
    f32x4 wv[32];
    {
        const f32x4* wrow = (const f32x4*)(Whh + (size_t)(g * HID_ + u0 + r32) * HID_ + kh * 128);
        #pragma unroll
        for (int i = 0; i < 32; ++i) wv[i] = wrow[i];
    }
    __syncthreads();

    const int eu = tid & 31;           // epilogue unit
    const int eb = tid >> 5;           // epilogue batch (valid for tid<128)

    // poll-read targets: 4 packed words per thread, issued concurrently
    int pb[4], pk[4];
    #pragma unroll
    for (int i = 0; i < 4; ++i) {
        const int idx = i * 256 + tid;   // 0..1023
        pb[i] = idx >> 8; pk[i] = idx & 255;
    }

    for (int t = 0; t < T_; ++t) {
        const int t_eff = dir ? (T_ - 1 - t) : t;

        // force the weight VGPRs live at loop top (loads cannot sink)
        #pragma unroll
        for (int i = 0; i < 32; ++i) asm volatile("" : "+v"(wv[i]));

        // xp prefetch first: its latency overlaps the poll below
        float x0 = 0.f, x1 = 0.f, x2 = 0.f, x3 = 0.f;
        if (tid < 128) {
            const float* xrow = xpd + ((size_t)t_eff * B_ + (b0 + eb)) * G_ + (u0 + eu);
            x0 = xrow[0]; x1 = xrow[HID_]; x2 = xrow[2 * HID_]; x3 = xrow[3 * HID_];
        }

        if (t > 0) {
            // poll the packed h words until their epoch tag == t
            const unsigned want = (unsigned)t;
            u64 v[4];
            #pragma unroll
            for (int i = 0; i < 4; ++i)
                v[i] = __hip_atomic_load(&xc[(size_t)pb[i] * HID_ + pk[i]],
                                         __ATOMIC_RELAXED, __HIP_MEMORY_SCOPE_AGENT);
            while ((unsigned)(v[0] >> 32) != want || (unsigned)(v[1] >> 32) != want ||
                   (unsigned)(v[2] >> 32) != want || (unsigned)(v[3] >> 32) != want) {
                #pragma unroll
                for (int i = 0; i < 4; ++i)
                    if ((unsigned)(v[i] >> 32) != want)
                        v[i] = __hip_atomic_load(&xc[(size_t)pb[i] * HID_ + pk[i]],
                                                 __ATOMIC_RELAXED, __HIP_MEMORY_SCOPE_AGENT);
            }
            #pragma unroll
            for (int i = 0; i < 4; ++i)
                hs[pb[i]][(pk[i] >> 7) * 132 + (pk[i] & 127)] =
                    __uint_as_float((unsigned)v[i]);
        }
        __syncthreads();   // S1: hs ready (also: prior-step Cg reads all done)

        // gate GEMM: Cg[g][u][b] = sum_k Whh[g*256+u0+u][k] * h_prev[b][k]
        #pragma unroll
        for (int b = 0; b < BPC; ++b) {
            const f32x4* hv = (const f32x4*)&hs[b][kh * 132];
            float acc = 0.f;
            #pragma unroll
            for (int i = 0; i < 32; ++i) {
                const f32x4 w4 = wv[i];
                const f32x4 h4 = hv[i];
                acc += w4.x * h4.x + w4.y * h4.y + w4.z * h4.z + w4.w * h4.w;
            }
            acc += __shfl_xor(acc, 32);
            if (kh == 0) Cg[g][r32][b] = acc;
        }
        __syncthreads();   // S2: Cg ready

        if (tid < 128) {
            const float gi = Cg[0][eu][eb] + x0;
            const float gf = Cg[1][eu][eb] + x1;
            const float gg = Cg[2][eu][eb] + x2;
            const float go = Cg[3][eu][eb] + x3;
            const float i_ = 1.f / (1.f + __expf(-gi));
            const float f_ = 1.f / (1.f + __expf(-gf));
            const float g_ = tanhf(gg);
            const float o_ = 1.f / (1.f + __expf(-go));
            const float cn = f_ * cs[eb][eu] + i_ * g_;
            const float hn = o_ * tanhf(cn);
            cs[eb][eu] = cn;
            // publish packed (tag|h) for peers; plain store for history
            if (t + 1 < T_) {
                const u64 pkv = ((u64)(unsigned)(t + 1) << 32) | __float_as_uint(hn);
                __hip_atomic_store(&xc[(size_t)eb * HID_ + (u0 + eu)], pkv,
                                   __ATOMIC_RELAXED, __HIP_MEMORY_SCOPE_AGENT);
            }
            hdir[((size_t)t_eff * B_ + (b0 + eb)) * HID_ + (u0 + eu)] = hn;
        }
        // no barrier here: next S1 orders everything
    }
}

// ---------------------------------------------------------------------------
// Kernel 3: emissions[t,b,l] = b_top[l] + h_f . W_top[l,:256] + h_b . W_top[l,256:]
// ---------------------------------------------------------------------------
__global__ __launch_bounds__(256) void k_emis(
    const float* __restrict__ Wt, const float* __restrict__ bt,
    const float* __restrict__ hbuf, float* __restrict__ em)
{
    const int gid = blockIdx.x * 256 + threadIdx.x;
    if (gid >= M_ * L_) return;
    const int m = gid / L_;
    const int l = gid - m * L_;
    const float4* hf  = (const float4*)(hbuf + (size_t)m * HID_);
    const float4* hbk = (const float4*)(hbuf + (size_t)M_ * HID_ + (size_t)m * HID_);
    const float4* w0  = (const float4*)(Wt + (size_t)l * 2 * HID_);
    const float4* w1  = w0 + HID_ / 4;
    float acc = bt[l];
    #pragma unroll 4
    for (int k = 0; k < HID_ / 4; ++k) {
        float4 h = hf[k],  w = w0[k];
        acc += h.x*w.x + h.y*w.y + h.z*w.z + h.w*w.w;
        h = hbk[k]; w = w1[k];
        acc += h.x*w.x + h.y*w.y + h.z*w.z + h.w*w.w;
    }
    em[gid] = acc;
}

// ---------------------------------------------------------------------------
// Kernel 4: CRF per-sequence forward + gold score. One block per b.
// ---------------------------------------------------------------------------
__global__ __launch_bounds__(64) void k_crf(
    const float* __restrict__ start_t, const float* __restrict__ end_t,
    const float* __restrict__ trans,
    const int* __restrict__ sent, const int* __restrict__ labels,
    const float* __restrict__ em, float* __restrict__ res)
{
    const int b = blockIdx.x;
    const int tid = threadIdx.x;
    __shared__ float tr[L_ * L_];
    __shared__ float alpha[2][L_];
    __shared__ float red[64];
    __shared__ int   redi[64];
    __shared__ float sdenom;

    for (int i = tid; i < L_ * L_; i += 64) tr[i] = trans[i];
    if (tid < L_) alpha[0][tid] = start_t[tid] + em[b * L_ + tid];
    __syncthreads();

    float pre_em = (tid < L_) ? em[(B_ + b) * L_ + tid] : 0.f;
    int   pre_m  = sent[B_ + b];

    int p = 0;
    for (int t = 1; t < T_; ++t) {
        const float emt = pre_em;
        const int   mt  = pre_m;
        if (t + 1 < T_) {
            if (tid < L_) pre_em = em[((t + 1) * B_ + b) * L_ + tid];
            pre_m = sent[(t + 1) * B_ + b];
        }
        float val = 0.f;
        if (tid < L_) {
            if (mt != 0) {
                float mx = -1e30f;
                #pragma unroll
                for (int i = 0; i < L_; ++i) mx = fmaxf(mx, alpha[p][i] + tr[i * L_ + tid]);
                float s = 0.f;
                #pragma unroll
                for (int i = 0; i < L_; ++i) s += __expf(alpha[p][i] + tr[i * L_ + tid] - mx);
                val = mx + __logf(s) + emt;
            } else {
                val = alpha[p][tid];
            }
        }
        if (tid < L_) alpha[1 - p][tid] = val;
        __syncthreads();
        p ^= 1;
    }

    if (tid == 0) {
        float mx = -1e30f;
        for (int j = 0; j < L_; ++j) mx = fmaxf(mx, alpha[p][j] + end_t[j]);
        float s = 0.f;
        for (int j = 0; j < L_; ++j) s += __expf(alpha[p][j] + end_t[j] - mx);
        sdenom = mx + __logf(s);
    }

    float loc = 0.f;
    int   cnt = 0;
    for (int t = tid; t < T_; t += 64) {
        const int masked = (sent[t * B_ + b] != 0);
        cnt += masked;
        if (t >= 1 && masked) {
            const int tp = labels[(t - 1) * B_ + b];
            const int tc = labels[t * B_ + b];
            loc += tr[tp * L_ + tc] + em[(t * B_ + b) * L_ + tc];
        }
    }
    red[tid] = loc; redi[tid] = cnt;
    __syncthreads();
    if (tid == 0) {
        float s = 0.f; int c = 0;
        for (int i = 0; i < 64; ++i) { s += red[i]; c += redi[i]; }
        const int tag0 = labels[b];
        const int seq_end = c - 1;
        const int last = labels[seq_end * B_ + b];
        const float score = start_t[tag0] + em[b * L_ + tag0] + s + end_t[last];
        res[b] = score - sdenom;
    }
}

// ---------------------------------------------------------------------------
// Kernel 5: out[0] = -sum_b res[b]
// ---------------------------------------------------------------------------
__global__ __launch_bounds__(64) void k_final(const float* __restrict__ res,
                                              float* __restrict__ out)
{
    __shared__ float red[64];
    red[threadIdx.x] = res[threadIdx.x];
    __syncthreads();
    if (threadIdx.x == 0) {
        float s = 0.f;
        for (int i = 0; i < 64; ++i) s += red[i];
        out[0] = -s;
    }
}

// ---------------------------------------------------------------------------
extern "C" void kernel_launch(void* const* d_in, const int* in_sizes, int n_in,
                              void* d_out, int out_size, void* d_ws, size_t ws_size,
                              hipStream_t stream)
{
    const float* emb     = (const float*)d_in[0];
    const float* Wih_f   = (const float*)d_in[1];
    const float* Whh_f   = (const float*)d_in[2];
    const float* b_f     = (const float*)d_in[3];
    const float* Wih_b   = (const float*)d_in[4];
    const float* Whh_b   = (const float*)d_in[5];
    const float* b_b     = (const float*)d_in[6];
    const float* W_top   = (const float*)d_in[7];
    const float* b_top   = (const float*)d_in[8];
    const float* start_t = (const float*)d_in[9];
    const float* end_t   = (const float*)d_in[10];
    const float* trans   = (const float*)d_in[11];
    const int*   sent    = (const int*)d_in[12];
    const int*   labels  = (const int*)d_in[13];
    float* out = (float*)d_out;

    float* wsf  = (float*)d_ws;
    float* xp   = wsf;                                   // 2*M*G floats
    float* hbuf = xp   + (size_t)2 * M_ * G_;            // 2*M*H
    float* em   = hbuf + (size_t)2 * M_ * HID_;          // M*L
    float* res  = em   + (size_t)M_ * L_;                // B
    u64*   xch  = (u64*)(res + 64);                      // 2*B*H packed words

    // 1) input projection GEMM (both dirs)
    k_xproj<<<dim3(2048 / 64, M_ / 64), 256, 0, stream>>>(
        emb, Wih_f, b_f, Wih_b, b_b, sent, xp);

    // 2) whole bidirectional scan, one cooperative launch
    //    (xch needs NO init: tags are 1..255, ws poison 0xAA never matches)
    {
        void* args[] = { (void*)&Whh_f, (void*)&Whh_b, (void*)&xp, (void*)&hbuf, (void*)&xch };
        hipLaunchCooperativeKernel((const void*)k_lstm_scan, dim3(256), dim3(256),
                                   args, 0, stream);
    }

    // 3) emissions
    k_emis<<<(M_ * L_ + 255) / 256, 256, 0, stream>>>(W_top, b_top, hbuf, em);

    // 4) CRF per-sequence
    k_crf<<<B_, 64, 0, stream>>>(start_t, end_t, trans, sent, labels, em, res);

    // 5) final sum
    k_final<<<1, 64, 0, stream>>>(res, out);
}